// Round 3
// baseline (187.143 us; speedup 1.0000x reference)
//
#include <hip/hip_runtime.h>
#include <hip/hip_bf16.h>
#include <hip/hip_fp16.h>
#include <cstdint>

#define NT      32768
#define DIN     256
#define DHID    1024
#define DOUT    256
#define NPLANES 8
#define NBLK    (NT / 256)     // 128 bucketing blocks

typedef unsigned short u16;
typedef __attribute__((ext_vector_type(8))) _Float16 f16x8;
typedef __attribute__((ext_vector_type(4))) float    f32x4;

// ---------------- workspace layout (bytes) ----------------
#define WS_OFFSETS  0                          // 9 ints
#define WS_META     64                         // 1 int (tile count)
#define WS_TILEP    512                        // 264 ints
#define WS_TILEM    2048                       // 264 ints
#define WS_BLKHIST  4096                       // NBLK*8 ints
#define WS_BLKBASE  (WS_BLKHIST + NBLK*8*4)    // NBLK*8 ints
#define WS_PERM     (WS_BLKBASE + NBLK*8*4)    // NT ints
#define WS_XB       (WS_PERM + NT*4)           // NT*DIN f16 (PERMUTED/bucketed order)
#define WS_W1B      (WS_XB  + NT*DIN*2)        // L*DHID*DIN f16
#define WS_W2B      (WS_W1B + NPLANES*DHID*DIN*2)
#define WS_HB       (WS_W2B + NPLANES*DOUT*DHID*2)  // NT*DHID f16 (bucketed)

__device__ __forceinline__ u16 f2h_bits(float f) {
    __half h = __float2half(f);
    return *reinterpret_cast<u16*>(&h);
}

__device__ __forceinline__ void gl_lds16(const void* g, void* l) {
    __builtin_amdgcn_global_load_lds(
        (const __attribute__((address_space(1))) void*)g,
        (__attribute__((address_space(3))) void*)l,
        16, 0, 0);
}

// ---------------- bucketing (atomic-free, deterministic) ----------------
__global__ void hist_k(const int* __restrict__ pidx, int* __restrict__ blkhist) {
    __shared__ int cnt[NPLANES];
    const int t = threadIdx.x, lane = t & 63;
    if (t < NPLANES) cnt[t] = 0;
    __syncthreads();
    const int p = pidx[blockIdx.x * 256 + t];
#pragma unroll
    for (int q = 0; q < NPLANES; ++q) {
        unsigned long long m = __ballot(p == q);
        if (p == q && __popcll(m & ((1ULL << lane) - 1)) == 0)
            atomicAdd(&cnt[q], __popcll(m));   // LDS atomic, 1/wave/plane
    }
    __syncthreads();
    if (t < NPLANES) blkhist[blockIdx.x * NPLANES + t] = cnt[t];
}

__global__ void scan_k(const int* __restrict__ blkhist, int* __restrict__ offsets,
                       int* __restrict__ blkbase, int* __restrict__ meta,
                       int* __restrict__ tileP, int* __restrict__ tileM) {
    __shared__ int tot[NPLANES];
    const int t = threadIdx.x;
    if (t < NPLANES) {
        int s = 0;
#pragma unroll 8
        for (int b = 0; b < NBLK; ++b) s += blkhist[b * NPLANES + t];
        tot[t] = s;
    }
    __syncthreads();
    if (t == 0) {
        int off = 0, tc = 0;
        for (int p = 0; p < NPLANES; ++p) {
            offsets[p] = off;
            for (int m = 0; m < tot[p]; m += 128) { tileP[tc] = p; tileM[tc] = m; ++tc; }
            off += tot[p];
        }
        offsets[NPLANES] = off;
        meta[0] = tc;
    }
    __syncthreads();
    if (t < NPLANES) {
        int run = offsets[t];
#pragma unroll 8
        for (int b = 0; b < NBLK; ++b) {
            blkbase[b * NPLANES + t] = run;
            run += blkhist[b * NPLANES + t];
        }
    }
}

__global__ void scatter_k(const int* __restrict__ pidx, const int* __restrict__ blkbase,
                          int* __restrict__ perm) {
    __shared__ int wcnt[4][NPLANES];
    __shared__ int wbase[4][NPLANES];
    const int t = threadIdx.x, lane = t & 63, wave = t >> 6;
    const int i = blockIdx.x * 256 + t;
    const int p = pidx[i];
    int rank = 0;
#pragma unroll
    for (int q = 0; q < NPLANES; ++q) {
        unsigned long long m = __ballot(p == q);
        if (lane == 0) wcnt[wave][q] = __popcll(m);
        if (p == q) rank = __popcll(m & ((1ULL << lane) - 1));
    }
    __syncthreads();
    if (t < NPLANES) {
        int run = blkbase[blockIdx.x * NPLANES + t];
#pragma unroll
        for (int w = 0; w < 4; ++w) { wbase[w][t] = run; run += wcnt[w][t]; }
    }
    __syncthreads();
    perm[wbase[wave][p] + rank] = i;   // blkbase already includes offsets[p]
}

// ---------------- converts ----------------
// x: f32 -> f16 AND permute into bucketed order (gather folded into BW-bound pass)
__global__ void cvtx_k(const float* __restrict__ x, const int* __restrict__ perm,
                       u16* __restrict__ xb) {
    const int n4 = NT * DIN / 4;
    const int stride = gridDim.x * blockDim.x;
    for (int i = blockIdx.x * blockDim.x + threadIdx.x; i < n4; i += stride) {
        const int row = i >> 6;          // DIN/4 = 64 float4 per row
        const int c4  = i & 63;
        const int src = perm[row];       // L1-cached, 64 lanes share
        float4 v = reinterpret_cast<const float4*>(x)[src * 64 + c4];
        ushort4 o;
        o.x = f2h_bits(v.x); o.y = f2h_bits(v.y);
        o.z = f2h_bits(v.z); o.w = f2h_bits(v.w);
        reinterpret_cast<ushort4*>(xb)[i] = o;
    }
}

// W1 + W2 fused convert
__global__ void cvtw_k(const float* __restrict__ W1, const float* __restrict__ W2,
                       u16* __restrict__ w1b, u16* __restrict__ w2b) {
    const int n1 = NPLANES * DHID * DIN / 4;
    const int n2 = NPLANES * DOUT * DHID / 4;
    const int stride = gridDim.x * blockDim.x;
    for (int i = blockIdx.x * blockDim.x + threadIdx.x; i < n1 + n2; i += stride) {
        const float4* s; ushort4* d; int j;
        if (i < n1) { s = (const float4*)W1; d = (ushort4*)w1b; j = i; }
        else        { s = (const float4*)W2; d = (ushort4*)w2b; j = i - n1; }
        float4 v = s[j];
        ushort4 o;
        o.x = f2h_bits(v.x); o.y = f2h_bits(v.y);
        o.z = f2h_bits(v.z); o.w = f2h_bits(v.w);
        d[j] = o;
    }
}

// ---------------- grouped GEMM, 2-phase double-buffered (T3 minimum recipe) ----
// LAYER1: A = xb (bucketed), B = w1b[p] (DHID x DIN), out = gelu -> hb (f16, bucketed)
// LAYER2: A = hb (bucketed), B = w2b[p] (DOUT x DHID), out = f32 scattered via perm
template<bool LAYER1>
__global__ __launch_bounds__(256, 2) void gemm_k(
    const u16* __restrict__ A, const u16* __restrict__ Bw,
    const float* __restrict__ bias, const int* __restrict__ perm,
    const int* __restrict__ offsets, const int* __restrict__ meta,
    const int* __restrict__ tileP, const int* __restrict__ tileM,
    void* __restrict__ Out)
{
    constexpr int K  = LAYER1 ? DIN : DHID;
    constexpr int ND = LAYER1 ? DHID : DOUT;
    constexpr int BK = 64;
    constexpr int KT = K / BK;

    if ((int)blockIdx.y >= meta[0]) return;
    const int p   = tileP[blockIdx.y];
    const int m0  = tileM[blockIdx.y];
    const int off = offsets[p];
    const int cnt = offsets[p + 1] - off;
    const int n0  = blockIdx.x * 128;

    __shared__ __align__(16) u16 sA[2][128 * BK];
    __shared__ __align__(16) u16 sB[2][128 * BK];

    const int tid  = threadIdx.x;
    const int srow = tid >> 3;   // 0..31
    const int sch  = tid & 7;    // 16B chunk slot 0..7

    // staging source pointers; global pre-swizzled so linear LDS dest = XOR-swizzled layout
    const u16* aptr[4];
    const u16* bptr[4];
#pragma unroll
    for (int i = 0; i < 4; ++i) {
        const int r  = i * 32 + srow;
        int gr = m0 + r; if (gr > cnt - 1) gr = cnt - 1;
        aptr[i] = A + (size_t)(off + gr) * K + (size_t)((sch ^ (r & 7)) * 8);
        bptr[i] = Bw + ((size_t)p * ND + n0 + r) * K + (size_t)((sch ^ (r & 7)) * 8);
    }

    const int wave = tid >> 6;
    const int lane = tid & 63;
    const int wm   = (wave >> 1) * 64;
    const int wn   = (wave & 1) * 64;
    const int lm   = lane & 15;
    const int lk   = lane >> 4;   // 0..3

    f32x4 acc[4][4];
#pragma unroll
    for (int a = 0; a < 4; ++a)
#pragma unroll
        for (int b = 0; b < 4; ++b) acc[a][b] = (f32x4){0.f, 0.f, 0.f, 0.f};

    // prologue: stage tile 0
#pragma unroll
    for (int i = 0; i < 4; ++i) {
        gl_lds16(aptr[i], &sA[0][i * 2048 + tid * 8]);
        gl_lds16(bptr[i], &sB[0][i * 2048 + tid * 8]);
    }
    __syncthreads();    // vmcnt(0) drain + barrier: buf0 ready

    int cur = 0;
    for (int kt = 0; kt < KT; ++kt) {
        // issue next tile's loads into buf^1 BEFORE computing current tile
        if (kt + 1 < KT) {
            const int k0 = (kt + 1) * BK;
#pragma unroll
            for (int i = 0; i < 4; ++i) {
                gl_lds16(aptr[i] + k0, &sA[cur ^ 1][i * 2048 + tid * 8]);
                gl_lds16(bptr[i] + k0, &sB[cur ^ 1][i * 2048 + tid * 8]);
            }
        }
        const u16* bufA = &sA[cur][0];
        const u16* bufB = &sB[cur][0];
#pragma unroll
        for (int kk = 0; kk < 2; ++kk) {
            f16x8 af[4], bfr[4];
#pragma unroll
            for (int mf = 0; mf < 4; ++mf) {
                const int row = wm + mf * 16 + lm;
                const int g   = kk * 4 + lk;
                af[mf] = *reinterpret_cast<const f16x8*>(bufA + row * BK + ((g ^ (row & 7)) * 8));
            }
#pragma unroll
            for (int nf = 0; nf < 4; ++nf) {
                const int row = wn + nf * 16 + lm;
                const int g   = kk * 4 + lk;
                bfr[nf] = *reinterpret_cast<const f16x8*>(bufB + row * BK + ((g ^ (row & 7)) * 8));
            }
#pragma unroll
            for (int mf = 0; mf < 4; ++mf)
#pragma unroll
                for (int nf = 0; nf < 4; ++nf)
                    acc[mf][nf] = __builtin_amdgcn_mfma_f32_16x16x32_f16(
                        af[mf], bfr[nf], acc[mf][nf], 0, 0, 0);
        }
        // drains this wave's vmcnt (next-tile stage) + lgkmcnt (frag reads), then barrier:
        // next buffer is fully written, current buffer safe to overwrite next iter.
        __syncthreads();
        cur ^= 1;
    }

    // epilogue: C/D layout col=lane&15, row=(lane>>4)*4+j
#pragma unroll
    for (int nf = 0; nf < 4; ++nf) {
        const int col = n0 + wn + nf * 16 + lm;
        const float bb = bias[p * ND + col];
#pragma unroll
        for (int mf = 0; mf < 4; ++mf) {
            f32x4 v = acc[mf][nf];
#pragma unroll
            for (int j = 0; j < 4; ++j) {
                const int ml = wm + mf * 16 + (lane >> 4) * 4 + j;
                const int gr = m0 + ml;
                if (gr < cnt) {
                    float xv = v[j] + bb;
                    if (LAYER1) {
                        float g = 0.5f * xv * (1.0f + erff(xv * 0.70710678118654752f));
                        ((u16*)Out)[(size_t)(off + gr) * DHID + col] = f2h_bits(g);
                    } else {
                        ((float*)Out)[(size_t)perm[off + gr] * DOUT + col] = xv;
                    }
                }
            }
        }
    }
}

// ---------------- launch ----------------
extern "C" void kernel_launch(void* const* d_in, const int* in_sizes, int n_in,
                              void* d_out, int out_size, void* d_ws, size_t ws_size,
                              hipStream_t stream) {
    const float* x    = (const float*)d_in[0];
    const float* W1   = (const float*)d_in[1];
    const float* b1   = (const float*)d_in[2];
    const float* W2   = (const float*)d_in[3];
    const float* b2   = (const float*)d_in[4];
    const int*   pidx = (const int*)d_in[5];
    float*       out  = (float*)d_out;

    char* ws      = (char*)d_ws;
    int* offsets  = (int*)(ws + WS_OFFSETS);
    int* meta     = (int*)(ws + WS_META);
    int* tileP    = (int*)(ws + WS_TILEP);
    int* tileM    = (int*)(ws + WS_TILEM);
    int* blkhist  = (int*)(ws + WS_BLKHIST);
    int* blkbase  = (int*)(ws + WS_BLKBASE);
    int* perm     = (int*)(ws + WS_PERM);
    u16* xb       = (u16*)(ws + WS_XB);
    u16* w1b      = (u16*)(ws + WS_W1B);
    u16* w2b      = (u16*)(ws + WS_W2B);
    u16* hb       = (u16*)(ws + WS_HB);

    hist_k<<<NBLK, 256, 0, stream>>>(pidx, blkhist);
    scan_k<<<1, 64, 0, stream>>>(blkhist, offsets, blkbase, meta, tileP, tileM);
    scatter_k<<<NBLK, 256, 0, stream>>>(pidx, blkbase, perm);

    cvtw_k<<<2048, 256, 0, stream>>>(W1, W2, w1b, w2b);
    cvtx_k<<<2048, 256, 0, stream>>>(x, perm, xb);

    gemm_k<true ><<<dim3(DHID / 128, 264, 1), 256, 0, stream>>>(
        xb, w1b, b1, perm, offsets, meta, tileP, tileM, (void*)hb);
    gemm_k<false><<<dim3(DOUT / 128, 264, 1), 256, 0, stream>>>(
        hb, w2b, b2, perm, offsets, meta, tileP, tileM, (void*)out);
}